// Round 1
// baseline (285.434 us; speedup 1.0000x reference)
//
#include <hip/hip_runtime.h>

typedef _Float16 f16x8 __attribute__((ext_vector_type(8)));
typedef float f32x4 __attribute__((ext_vector_type(4)));

#define D_IN 768
#define D_H  256
#define SEQ  2048

// ---------------- K0: W1 [768][256] f32 -> W1T [256][768] f16 (transposed) ---
__global__ __launch_bounds__(256) void k0_w1t(const float* __restrict__ W1,
                                              _Float16* __restrict__ W1T) {
  __shared__ float tl[64][65];
  const int kb = blockIdx.x, nb = blockIdx.y, t = threadIdx.x;
#pragma unroll
  for (int rep = 0; rep < 16; ++rep) {
    const int row = rep * 4 + (t >> 6), col = t & 63;
    tl[row][col] = W1[(size_t)(kb * 64 + row) * D_H + nb * 64 + col];
  }
  __syncthreads();
#pragma unroll
  for (int rep = 0; rep < 16; ++rep) {
    const int n = rep * 4 + (t >> 6), k = t & 63;
    W1T[(size_t)(nb * 64 + n) * D_IN + kb * 64 + k] = (_Float16)tl[k][n];
  }
}

// ---------------- K1: logits[b][c][s] = tanh(X@W1+b1) @ C --------------------
// 1024 blocks x 512 threads. Block tile: 128 rows x 256 cols (full N).
// fp16 MFMA 16x16x32, BK=64, register-prefetch single-LDS-buffer pipeline.
__global__ __launch_bounds__(512) void k1_logits(const float* __restrict__ X,
    const _Float16* __restrict__ W1T, const float* __restrict__ b1,
    const float* __restrict__ C, float* __restrict__ logits) {
  __shared__ _Float16 Al[128][72];   // [row][k], +8 pad -> 2-way banks on b128
  __shared__ _Float16 Bl[256][72];   // [col][k]
  __shared__ float red[4][32][4];
  const int t = threadIdx.x;
  const int M0 = blockIdx.x * 128;

  const int arow = t >> 2, akc = t & 3;          // A stage: row, k-chunks akc, akc+4
  const int bcol = t >> 1, bko = (t & 1) * 32;   // B stage: col, 32 halves
  const float*    Ag = X + (size_t)(M0 + arow) * D_IN + akc * 8;
  const _Float16* Bg = W1T + (size_t)bcol * D_IN + bko;

  f32x4 acc[2][8];
#pragma unroll
  for (int i = 0; i < 2; ++i)
#pragma unroll
    for (int j = 0; j < 8; ++j) acc[i][j] = f32x4{0.f, 0.f, 0.f, 0.f};

  float4 a0 = *(const float4*)(Ag);
  float4 a1 = *(const float4*)(Ag + 4);
  float4 a2 = *(const float4*)(Ag + 32);
  float4 a3 = *(const float4*)(Ag + 36);
  uint4 bb0 = *(const uint4*)(Bg);
  uint4 bb1 = *(const uint4*)(Bg + 8);
  uint4 bb2 = *(const uint4*)(Bg + 16);
  uint4 bb3 = *(const uint4*)(Bg + 24);

  const int lane = t & 63, wv = t >> 6;
  const int wm = wv >> 1, wn = wv & 1;           // 4 m-waves x 2 n-waves
  const int l15 = lane & 15, kg = lane >> 4;

  for (int kt = 0; kt < 12; ++kt) {
    f16x8 ha, hb;
    ha[0] = (_Float16)a0.x; ha[1] = (_Float16)a0.y; ha[2] = (_Float16)a0.z; ha[3] = (_Float16)a0.w;
    ha[4] = (_Float16)a1.x; ha[5] = (_Float16)a1.y; ha[6] = (_Float16)a1.z; ha[7] = (_Float16)a1.w;
    hb[0] = (_Float16)a2.x; hb[1] = (_Float16)a2.y; hb[2] = (_Float16)a2.z; hb[3] = (_Float16)a2.w;
    hb[4] = (_Float16)a3.x; hb[5] = (_Float16)a3.y; hb[6] = (_Float16)a3.z; hb[7] = (_Float16)a3.w;
    *(f16x8*)&Al[arow][akc * 8]      = ha;
    *(f16x8*)&Al[arow][akc * 8 + 32] = hb;
    *(uint4*)&Bl[bcol][bko]      = bb0;
    *(uint4*)&Bl[bcol][bko + 8]  = bb1;
    *(uint4*)&Bl[bcol][bko + 16] = bb2;
    *(uint4*)&Bl[bcol][bko + 24] = bb3;
    __syncthreads();
    if (kt < 11) {  // prefetch next tile into registers (overlaps compute)
      const float* An = Ag + (kt + 1) * 64;
      a0 = *(const float4*)(An);
      a1 = *(const float4*)(An + 4);
      a2 = *(const float4*)(An + 32);
      a3 = *(const float4*)(An + 36);
      const _Float16* Bn = Bg + (kt + 1) * 64;
      bb0 = *(const uint4*)(Bn);
      bb1 = *(const uint4*)(Bn + 8);
      bb2 = *(const uint4*)(Bn + 16);
      bb3 = *(const uint4*)(Bn + 24);
    }
#pragma unroll
    for (int st = 0; st < 2; ++st) {
      f16x8 af[2], bf[8];
#pragma unroll
      for (int i = 0; i < 2; ++i)
        af[i] = *(const f16x8*)&Al[wm * 32 + i * 16 + l15][kg * 8 + st * 32];
#pragma unroll
      for (int j = 0; j < 8; ++j)
        bf[j] = *(const f16x8*)&Bl[wn * 128 + j * 16 + l15][kg * 8 + st * 32];
#pragma unroll
      for (int j = 0; j < 8; ++j)
#pragma unroll
        for (int i = 0; i < 2; ++i)
          acc[i][j] = __builtin_amdgcn_mfma_f32_16x16x32_f16(af[i], bf[j], acc[i][j], 0, 0, 0);
    }
    __syncthreads();
  }

  // Epilogue: z=acc+b1, h=tanh(z), project onto 4 context vectors, reduce.
  ((float*)red)[t] = 0.f;
  __syncthreads();

  float part[2][4][4];
#pragma unroll
  for (int i = 0; i < 2; ++i)
#pragma unroll
    for (int r = 0; r < 4; ++r)
#pragma unroll
      for (int c = 0; c < 4; ++c) part[i][r][c] = 0.f;

#pragma unroll
  for (int j = 0; j < 8; ++j) {
    const int col = wn * 128 + j * 16 + l15;
    const float4 c4 = *(const float4*)(C + col * 4);
    const float bv = b1[col];
#pragma unroll
    for (int i = 0; i < 2; ++i)
#pragma unroll
      for (int r = 0; r < 4; ++r) {
        float z = acc[i][j][r] + bv;
        z = fminf(fmaxf(z, -15.f), 15.f);
        const float e = __expf(2.f * z);
        const float h = (e - 1.f) / (e + 1.f);   // tanh(z)
        part[i][r][0] += h * c4.x;
        part[i][r][1] += h * c4.y;
        part[i][r][2] += h * c4.z;
        part[i][r][3] += h * c4.w;
      }
  }
  // butterfly-reduce over the 16 column-lanes
#pragma unroll
  for (int off = 1; off < 16; off <<= 1) {
#pragma unroll
    for (int i = 0; i < 2; ++i)
#pragma unroll
      for (int r = 0; r < 4; ++r)
#pragma unroll
        for (int c = 0; c < 4; ++c)
          part[i][r][c] += __shfl_xor(part[i][r][c], off, 64);
  }
  if (l15 == 0) {
#pragma unroll
    for (int i = 0; i < 2; ++i)
#pragma unroll
      for (int r = 0; r < 4; ++r)
#pragma unroll
        for (int c = 0; c < 4; ++c)
          atomicAdd(&red[wm][i * 16 + kg * 4 + r][c], part[i][r][c]);
  }
  __syncthreads();
  {
    const int wmx = t >> 7, row = (t >> 2) & 31, c = t & 3;
    const int m = M0 + wmx * 32 + row;
    const int b = m >> 11, s = m & 2047;
    logits[((size_t)(b * 4 + c)) * SEQ + s] = red[wmx][row][c];
  }
}

// ---------------- K2: softmax over s -> scores[b][s][c] (float4) -------------
__global__ __launch_bounds__(256) void k2_softmax(const float* __restrict__ logits,
                                                  float* __restrict__ scores) {
  const int b = blockIdx.x, t = threadIdx.x;
  const int lane = t & 63, wv = t >> 6;
  __shared__ float rmax[4][4], rsum[4][4];
  float lv[4][8];
#pragma unroll
  for (int c = 0; c < 4; ++c)
#pragma unroll
    for (int j = 0; j < 8; ++j)
      lv[c][j] = logits[((size_t)(b * 4 + c)) * SEQ + j * 256 + t];
#pragma unroll
  for (int c = 0; c < 4; ++c) {
    float m = lv[c][0];
#pragma unroll
    for (int j = 1; j < 8; ++j) m = fmaxf(m, lv[c][j]);
#pragma unroll
    for (int off = 1; off < 64; off <<= 1) m = fmaxf(m, __shfl_xor(m, off, 64));
    if (lane == 0) rmax[wv][c] = m;
  }
  __syncthreads();
  float mx[4], inv[4];
#pragma unroll
  for (int c = 0; c < 4; ++c)
    mx[c] = fmaxf(fmaxf(rmax[0][c], rmax[1][c]), fmaxf(rmax[2][c], rmax[3][c]));
#pragma unroll
  for (int c = 0; c < 4; ++c) {
    float ssum = 0.f;
#pragma unroll
    for (int j = 0; j < 8; ++j) { lv[c][j] = __expf(lv[c][j] - mx[c]); ssum += lv[c][j]; }
#pragma unroll
    for (int off = 1; off < 64; off <<= 1) ssum += __shfl_xor(ssum, off, 64);
    if (lane == 0) rsum[wv][c] = ssum;
  }
  __syncthreads();
#pragma unroll
  for (int c = 0; c < 4; ++c)
    inv[c] = 1.f / (rsum[0][c] + rsum[1][c] + rsum[2][c] + rsum[3][c]);
#pragma unroll
  for (int j = 0; j < 8; ++j) {
    float4 o;
    o.x = lv[0][j] * inv[0]; o.y = lv[1][j] * inv[1];
    o.z = lv[2][j] * inv[2]; o.w = lv[3][j] * inv[3];
    *(float4*)&scores[((size_t)b * SEQ + j * 256 + t) * 4] = o;
  }
}

// ---------------- K3: pooled[b][c*768+d] = relu(sum_s scores*X) --------------
// grid (6 d-chunks, 64 batches) x 256 thr; thread: 8-way s-parallel, float4 d.
__global__ __launch_bounds__(256) void k3_pool(const float* __restrict__ X,
                                               const float* __restrict__ scores,
                                               float* __restrict__ pooled) {
  const int chunk = blockIdx.x, b = blockIdx.y, t = threadIdx.x;
  const int s0 = t >> 5, d4 = t & 31;
  const float* Xb = X + (size_t)b * SEQ * D_IN + chunk * 128 + d4 * 4;
  const float* Sb = scores + (size_t)b * SEQ * 4;
  float acc[4][4];
#pragma unroll
  for (int c = 0; c < 4; ++c)
#pragma unroll
    for (int j = 0; j < 4; ++j) acc[c][j] = 0.f;
#pragma unroll 2
  for (int s = s0; s < SEQ; s += 8) {
    const float4 w = *(const float4*)(Sb + (size_t)s * 4);
    const float4 x = *(const float4*)(Xb + (size_t)s * D_IN);
    const float wc[4] = {w.x, w.y, w.z, w.w};
    const float xv[4] = {x.x, x.y, x.z, x.w};
#pragma unroll
    for (int c = 0; c < 4; ++c)
#pragma unroll
      for (int j = 0; j < 4; ++j) acc[c][j] += wc[c] * xv[j];
  }
  __shared__ float r3[8][32][16];
#pragma unroll
  for (int c = 0; c < 4; ++c)
#pragma unroll
    for (int j = 0; j < 4; ++j) r3[s0][d4][c * 4 + j] = acc[c][j];
  __syncthreads();
#pragma unroll
  for (int o = t; o < 512; o += 256) {
    const int dd = o >> 4, cj = o & 15, c = cj >> 2, j = cj & 3;
    float v = 0.f;
#pragma unroll
    for (int p = 0; p < 8; ++p) v += r3[p][dd][cj];
    v = fmaxf(v, 0.f);
    pooled[(size_t)b * 3072 + c * D_IN + chunk * 128 + dd * 4 + j] = v;
  }
}

// ---------------- K4: partial[kc][b][j] = pooled(k-slice) @ W2(k-slice) ------
// grid (12 j-chunks of 64, 16 k-chunks of 192); W2 read exactly once.
__global__ __launch_bounds__(256) void k4_partial(const float* __restrict__ pooled,
                                                  const float* __restrict__ W2,
                                                  float* __restrict__ partial) {
  const int jc = blockIdx.x, kc = blockIdx.y, t = threadIdx.x;
  __shared__ float plds[64 * 192];
  __shared__ float sum2[64][64];
  for (int idx = t; idx < 64 * 192; idx += 256) {
    const int b = idx / 192, k = idx - b * 192;
    plds[idx] = pooled[(size_t)b * 3072 + kc * 192 + k];
  }
  __syncthreads();
  const int j = t & 63, kp = t >> 6;
  float acc[64];
#pragma unroll
  for (int b = 0; b < 64; ++b) acc[b] = 0.f;
  const float* W2p = W2 + (size_t)(kc * 192 + kp * 48) * D_IN + jc * 64 + j;
  const float* pb = plds + kp * 48;
  for (int ki = 0; ki < 48; ki += 4) {
    const float w0 = W2p[(size_t)(ki + 0) * D_IN];
    const float w1 = W2p[(size_t)(ki + 1) * D_IN];
    const float w2 = W2p[(size_t)(ki + 2) * D_IN];
    const float w3 = W2p[(size_t)(ki + 3) * D_IN];
#pragma unroll
    for (int b = 0; b < 64; ++b) {
      const float4 p4 = *(const float4*)(pb + b * 192 + ki);
      acc[b] += p4.x * w0 + p4.y * w1 + p4.z * w2 + p4.w * w3;
    }
  }
#pragma unroll
  for (int p = 0; p < 4; ++p) {
    if (kp == p) {
      if (p == 0) {
#pragma unroll
        for (int b = 0; b < 64; ++b) sum2[b][j] = acc[b];
      } else {
#pragma unroll
        for (int b = 0; b < 64; ++b) sum2[b][j] += acc[b];
      }
    }
    __syncthreads();
  }
  for (int idx = t; idx < 4096; idx += 256) {
    const int b = idx >> 6, jj = idx & 63;
    partial[(size_t)kc * 49152 + (size_t)b * D_IN + jc * 64 + jj] = sum2[b][jj];
  }
}

// ---------------- K5: out = sum(partials) + b2 -------------------------------
__global__ __launch_bounds__(256) void k5_final(const float* __restrict__ partial,
                                                const float* __restrict__ b2,
                                                float* __restrict__ out) {
  const int o = blockIdx.x * 256 + threadIdx.x;
  float v = b2[o % D_IN];
#pragma unroll
  for (int p = 0; p < 16; ++p) v += partial[(size_t)p * 49152 + o];
  out[o] = v;
}

extern "C" void kernel_launch(void* const* d_in, const int* in_sizes, int n_in,
                              void* d_out, int out_size, void* d_ws, size_t ws_size,
                              hipStream_t stream) {
  const float* X  = (const float*)d_in[0];
  const float* W1 = (const float*)d_in[1];
  const float* b1 = (const float*)d_in[2];
  const float* C  = (const float*)d_in[3];
  const float* W2 = (const float*)d_in[4];
  const float* b2 = (const float*)d_in[5];
  float* out = (float*)d_out;
  char* ws = (char*)d_ws;
  _Float16* W1T  = (_Float16*)ws;             // 393,216 B
  float* logits  = (float*)(ws + 393216);     // 2,097,152 B  [64][4][2048]
  float* scores  = (float*)(ws + 2490368);    // 2,097,152 B  [64][2048][4]
  float* pooled  = (float*)(ws + 4587520);    //   786,432 B  [64][3072]
  float* partial = (float*)(ws + 5373952);    // 3,145,728 B  [16][64][768]

  k0_w1t   <<<dim3(12, 4), 256, 0, stream>>>(W1, W1T);
  k1_logits<<<1024,        512, 0, stream>>>(X, W1T, b1, C, logits);
  k2_softmax<<<64,         256, 0, stream>>>(logits, scores);
  k3_pool  <<<dim3(6, 64), 256, 0, stream>>>(X, scores, pooled);
  k4_partial<<<dim3(12,16),256, 0, stream>>>(pooled, W2, partial);
  k5_final <<<192,         256, 0, stream>>>(partial, b2, out);
}